// Round 5
// baseline (155.714 us; speedup 1.0000x reference)
//
#include <hip/hip_runtime.h>
#include <cmath>

#define NEG_INF (-1.0e30f)

static constexpr int B = 256;
static constexpr int N = 65536;
static constexpr int THREADS = 256;          // 4 waves/block
static constexpr float C_OFF = 40.96f;       // = 64 * 0.8^2, upper bound of both logits
static constexpr float PAD = 0.2f;           // exact pad: logit(v<=0.2) == 0 == logit(0.2)

typedef float f32x4 __attribute__((ext_vector_type(4)));

__device__ __forceinline__ float wave_sum_f(float v) {
#pragma unroll
  for (int off = 32; off >= 1; off >>= 1) v += __shfl_xor(v, off, 64);
  return v;
}

// Merge this lane's descending-sorted 16-list with XOR-partner lane's list,
// keeping the top-16 of the union (bitonic top-k merge).
__device__ __forceinline__ void merge_lists_shfl(float t[16], int off) {
  float b[16];
#pragma unroll
  for (int i = 0; i < 16; ++i) b[i] = __shfl_xor(t[i], off, 64);
  float c[16];
#pragma unroll
  for (int i = 0; i < 16; ++i) c[i] = fmaxf(t[i], b[15 - i]);
#pragma unroll
  for (int s = 8; s >= 1; s >>= 1) {
#pragma unroll
    for (int i = 0; i < 16; ++i) {
      if ((i & s) == 0) {
        float lo = c[i], hi = c[i + s];
        c[i] = fmaxf(lo, hi);
        c[i + s] = fminf(lo, hi);
      }
    }
  }
#pragma unroll
  for (int i = 0; i < 16; ++i) t[i] = c[i];
}

// Same top-16 merge, but between two register lists (no shuffle).
__device__ __forceinline__ void merge_lists_local(float a[16], const float b[16]) {
  float c[16];
#pragma unroll
  for (int i = 0; i < 16; ++i) c[i] = fmaxf(a[i], b[15 - i]);
#pragma unroll
  for (int s = 8; s >= 1; s >>= 1) {
#pragma unroll
    for (int i = 0; i < 16; ++i) {
      if ((i & s) == 0) {
        float lo = c[i], hi = c[i + s];
        c[i] = fmaxf(lo, hi);
        c[i + s] = fminf(lo, hi);
      }
    }
  }
#pragma unroll
  for (int i = 0; i < 16; ++i) a[i] = c[i];
}

__device__ __forceinline__ void process_elem(float s, float l, float& s_p,
                                             float& s_n, int& nn, float t[10]) {
  const bool pos = l > 0.5f;
  const bool neg = l < 0.25f;
  // logit_p = 64*relu(0.8-s)^2 ; logit_n = 64*relu(s-0.2)^2 (both in [0, 40.96])
  float d = pos ? (0.8f - s) : (s - 0.2f);
  float r = fmaxf(d, 0.f);
  float arg = __builtin_fmaf(64.f * r, r, -C_OFF);  // <= 0, finite for all s
  float e = __expf(arg);
  if (pos) s_p += e;
  if (neg) s_n += e;
  // wave-uniform negative count on the SALU (no per-lane VALU add)
  nn += (int)__popcll(__ballot(neg));
  // sorted-descending top-10 insert. se=PAD for non-neg never triggers
  // (t[9] >= PAD invariant). Insert via v_med3: r[i] = med3(se, told[i-1], told[i])
  float se = neg ? s : PAD;
  if (se > t[9]) {
    float prev = t[0];
    t[0] = fmaxf(t[0], se);
#pragma unroll
    for (int i = 1; i < 10; ++i) {
      float cur = t[i];
      t[i] = __builtin_amdgcn_fmed3f(se, prev, cur);
      prev = cur;
    }
  }
}

// One block per (row, part). Writes partial {sum_p, sum_n, count_n, top16}.
template <int SPLIT>
__global__ void __launch_bounds__(THREADS, 4) ranking_partial_kernel(
    const float* __restrict__ sim, const float* __restrict__ label,
    float* __restrict__ ws_sp, float* __restrict__ ws_sn,
    int* __restrict__ ws_cnt, float* __restrict__ ws_top) {
  const int blk = blockIdx.x;
  const int row = blk / SPLIT;
  const int part = blk % SPLIT;
  const int tid = threadIdx.x;
  const size_t base4 = (size_t)row * (N / 4) + (size_t)part * (N / (4 * SPLIT));
  const f32x4* sim4 = reinterpret_cast<const f32x4*>(sim) + base4;
  const f32x4* lab4 = reinterpret_cast<const f32x4*>(label) + base4;

  float s_p = 0.f, s_n = 0.f;
  int nn = 0;  // wave-uniform (ballot-popc accumulated)
  float t[10];
#pragma unroll
  for (int i = 0; i < 10; ++i) t[i] = PAD;

  constexpr int ITER = N / 4 / THREADS / SPLIT;   // 8 at SPLIT=8
  constexpr int PF = (ITER > 8) ? 8 : ITER;       // prefetch depth per chunk

#pragma unroll
  for (int base = 0; base < ITER; base += PF) {
    f32x4 sv[PF], lv[PF];
    // Phase 1: issue ALL loads of this chunk (2*PF dwordx4 in flight).
#pragma unroll
    for (int j = 0; j < PF; ++j) {
      sv[j] = sim4[(base + j) * THREADS + tid];
      lv[j] = lab4[(base + j) * THREADS + tid];
    }
    // Pin the prefetch: per-value keep-alives force every load to be issued
    // here (not re-sunk into the consume stream by the register-pressure
    // scheduler), then a hard scheduling fence.
#pragma unroll
    for (int j = 0; j < PF; ++j) {
      asm volatile("" : "+v"(sv[j][0]), "+v"(sv[j][1]), "+v"(sv[j][2]), "+v"(sv[j][3]));
      asm volatile("" : "+v"(lv[j][0]), "+v"(lv[j][1]), "+v"(lv[j][2]), "+v"(lv[j][3]));
    }
    __builtin_amdgcn_sched_barrier(0);
    // Phase 2: consume in load order -> incremental vmcnt waits, the rest
    // of the chunk stays in flight while we compute.
#pragma unroll
    for (int j = 0; j < PF; ++j) {
      process_elem(sv[j][0], lv[j][0], s_p, s_n, nn, t);
      process_elem(sv[j][1], lv[j][1], s_p, s_n, nn, t);
      process_elem(sv[j][2], lv[j][2], s_p, s_n, nn, t);
      process_elem(sv[j][3], lv[j][3], s_p, s_n, nn, t);
    }
  }

  // expand to 16-list for bitonic merges (pad 0.2 keeps descending order)
  float tl[16];
#pragma unroll
  for (int i = 0; i < 10; ++i) tl[i] = t[i];
#pragma unroll
  for (int i = 10; i < 16; ++i) tl[i] = PAD;

  // intra-wave reductions
  s_p = wave_sum_f(s_p);
  s_n = wave_sum_f(s_n);
#pragma unroll
  for (int off = 1; off < 64; off <<= 1) merge_lists_shfl(tl, off);

  __shared__ float ls_p[4], ls_n[4];
  __shared__ int ls_c[4];
  __shared__ float ltop[4][16];
  const int wave = tid >> 6, lane = tid & 63;
  if (lane == 0) {
    ls_p[wave] = s_p;
    ls_n[wave] = s_n;
    ls_c[wave] = nn;
#pragma unroll
    for (int i = 0; i < 16; ++i) ltop[wave][i] = tl[i];
  }
  __syncthreads();

  if (wave == 0) {
    // lanes 0..3 each hold one wave's top-16; butterfly-merge them
    float m[16];
    if (lane < 4) {
#pragma unroll
      for (int i = 0; i < 16; ++i) m[i] = ltop[lane][i];
    } else {
#pragma unroll
      for (int i = 0; i < 16; ++i) m[i] = PAD;
    }
    merge_lists_shfl(m, 1);
    merge_lists_shfl(m, 2);

    float sp = (lane < 4) ? ls_p[lane] : 0.f;
    float sn = (lane < 4) ? ls_n[lane] : 0.f;
    int cn = (lane < 4) ? ls_c[lane] : 0;
    sp = wave_sum_f(sp);
    sn = wave_sum_f(sn);
#pragma unroll
    for (int off = 32; off >= 1; off >>= 1) cn += __shfl_xor(cn, off, 64);

    if (lane == 0) {
      ws_sp[blk] = sp;
      ws_sn[blk] = sn;
      ws_cnt[blk] = cn;
#pragma unroll
      for (int i = 0; i < 16; ++i) ws_top[blk * 16 + i] = m[i];
    }
  }
}

// One block, 256 threads: thread r combines the SPLIT partials of row r,
// computes the row loss, then the block reduces to the final mean.
template <int SPLIT>
__global__ void __launch_bounds__(256) combine_kernel(
    const float* __restrict__ ws_sp, const float* __restrict__ ws_sn,
    const int* __restrict__ ws_cnt, const float* __restrict__ ws_top,
    float* __restrict__ out) {
  const int r = threadIdx.x;
  const int p0 = r * SPLIT;

  float a[16];
#pragma unroll
  for (int i = 0; i < 16; ++i) a[i] = ws_top[p0 * 16 + i];
#pragma unroll
  for (int k = 1; k < SPLIT; ++k) {
    float b[16];
#pragma unroll
    for (int i = 0; i < 16; ++i) b[i] = ws_top[(p0 + k) * 16 + i];
    merge_lists_local(a, b);  // a = running top-16, sorted descending
  }

  float sp = 0.f, sn = 0.f;
  int cn = 0;
#pragma unroll
  for (int k = 0; k < SPLIT; ++k) {
    sp += ws_sp[p0 + k];
    sn += ws_sn[p0 + k];
    cn += ws_cnt[p0 + k];
  }

  // any positives <=> sp > 0 (each pos term >= exp(-40.96) > 0)
  float lse_p = (sp > 0.f) ? (C_OFF + __logf(sp)) : 0.f;
  float lse_n_all = (sn > 0.f) ? (C_OFF + __logf(sn)) : NEG_INF;

  // top-10 logsumexp (a[0..9] = top-10 negative sims; pad 0.2 -> logit 0, exact)
  float mx = NEG_INF;
  float lg[10];
#pragma unroll
  for (int i = 0; i < 10; ++i) {
    float v = a[i];
    float al = fmaxf(v - 0.2f, 0.f);
    float lo = al * (v - 0.2f) * 64.f;
    lg[i] = lo;
    mx = fmaxf(mx, lo);
  }
  float ss = 0.f;
#pragma unroll
  for (int i = 0; i < 10; ++i) ss += __expf(lg[i] - mx);
  float lse_n_top = mx + __logf(ss);

  float lse_n = (cn > 20) ? lse_n_top : lse_n_all;
  float x = lse_n + lse_p;
  // softplus(x) = max(x,0) + log1p(exp(-|x|))
  float loss = fmaxf(x, 0.f) + log1pf(__expf(-fabsf(x)));

  // block reduction (256 threads = 4 waves)
  float v = wave_sum_f(loss);
  __shared__ float wsh[4];
  if ((r & 63) == 0) wsh[r >> 6] = v;
  __syncthreads();
  if (r == 0) out[0] = (wsh[0] + wsh[1] + wsh[2] + wsh[3]) * (1.0f / 256.0f);
}

template <int SPLIT>
static void launch_all(const float* sim, const float* label, float* out,
                       float* wsf, hipStream_t stream) {
  constexpr int P = B * SPLIT;
  float* ws_sp = wsf;
  float* ws_sn = wsf + P;
  float* ws_top = wsf + 2 * P;
  int* ws_cnt = (int*)(wsf + 2 * P + P * 16);
  ranking_partial_kernel<SPLIT><<<dim3(P), dim3(THREADS), 0, stream>>>(
      sim, label, ws_sp, ws_sn, ws_cnt, ws_top);
  combine_kernel<SPLIT><<<dim3(1), dim3(256), 0, stream>>>(ws_sp, ws_sn, ws_cnt,
                                                           ws_top, out);
}

extern "C" void kernel_launch(void* const* d_in, const int* in_sizes, int n_in,
                              void* d_out, int out_size, void* d_ws, size_t ws_size,
                              hipStream_t stream) {
  const float* sim = (const float*)d_in[0];
  const float* label = (const float*)d_in[1];
  float* out = (float*)d_out;
  float* wsf = (float*)d_ws;

  auto need = [](int split) { return (size_t)B * split * 19 * sizeof(float); };
  if (ws_size >= need(8)) {
    launch_all<8>(sim, label, out, wsf, stream);
  } else if (ws_size >= need(4)) {
    launch_all<4>(sim, label, out, wsf, stream);
  } else {
    launch_all<2>(sim, label, out, wsf, stream);
  }
}

// Round 6
// 153.360 us; speedup vs baseline: 1.0153x; 1.0153x over previous
//
#include <hip/hip_runtime.h>
#include <cmath>

#define NEG_INF (-1.0e30f)

static constexpr int B = 256;
static constexpr int N = 65536;
static constexpr int THREADS = 256;          // 4 waves/block
static constexpr float C_OFF = 40.96f;       // = 64 * 0.8^2, upper bound of both logits
static constexpr float PAD = 0.2f;           // exact pad: logit(v<=0.2) == 0 == logit(0.2)

typedef float f32x4 __attribute__((ext_vector_type(4)));

__device__ __forceinline__ float wave_sum_f(float v) {
#pragma unroll
  for (int off = 32; off >= 1; off >>= 1) v += __shfl_xor(v, off, 64);
  return v;
}

// Merge this lane's descending-sorted 16-list with XOR-partner lane's list,
// keeping the top-16 of the union (bitonic top-k merge).
__device__ __forceinline__ void merge_lists_shfl(float t[16], int off) {
  float b[16];
#pragma unroll
  for (int i = 0; i < 16; ++i) b[i] = __shfl_xor(t[i], off, 64);
  float c[16];
#pragma unroll
  for (int i = 0; i < 16; ++i) c[i] = fmaxf(t[i], b[15 - i]);
#pragma unroll
  for (int s = 8; s >= 1; s >>= 1) {
#pragma unroll
    for (int i = 0; i < 16; ++i) {
      if ((i & s) == 0) {
        float lo = c[i], hi = c[i + s];
        c[i] = fmaxf(lo, hi);
        c[i + s] = fminf(lo, hi);
      }
    }
  }
#pragma unroll
  for (int i = 0; i < 16; ++i) t[i] = c[i];
}

// Same top-16 merge, but between two register lists (no shuffle).
__device__ __forceinline__ void merge_lists_local(float a[16], const float b[16]) {
  float c[16];
#pragma unroll
  for (int i = 0; i < 16; ++i) c[i] = fmaxf(a[i], b[15 - i]);
#pragma unroll
  for (int s = 8; s >= 1; s >>= 1) {
#pragma unroll
    for (int i = 0; i < 16; ++i) {
      if ((i & s) == 0) {
        float lo = c[i], hi = c[i + s];
        c[i] = fmaxf(lo, hi);
        c[i + s] = fminf(lo, hi);
      }
    }
  }
#pragma unroll
  for (int i = 0; i < 16; ++i) a[i] = c[i];
}

__device__ __forceinline__ void process_elem(float s, float l, float& s_p,
                                             float& s_n, int& nn, float t[10]) {
  const bool pos = l > 0.5f;
  const bool neg = l < 0.25f;
  // logit_p = 64*relu(0.8-s)^2 ; logit_n = 64*relu(s-0.2)^2 (both in [0, 40.96])
  float d = pos ? (0.8f - s) : (s - 0.2f);
  float r = fmaxf(d, 0.f);
  float arg = __builtin_fmaf(64.f * r, r, -C_OFF);  // <= 0, finite for all s
  float e = __expf(arg);
  if (pos) s_p += e;
  if (neg) s_n += e;
  // wave-uniform negative count on the SALU (no per-lane VALU add)
  nn += (int)__popcll(__ballot(neg));
  // sorted-descending top-10 insert. se=PAD for non-neg never triggers
  // (t[9] >= PAD invariant). Insert via v_med3: r[i] = med3(se, told[i-1], told[i])
  float se = neg ? s : PAD;
  if (se > t[9]) {
    float prev = t[0];
    t[0] = fmaxf(t[0], se);
#pragma unroll
    for (int i = 1; i < 10; ++i) {
      float cur = t[i];
      t[i] = __builtin_amdgcn_fmed3f(se, prev, cur);
      prev = cur;
    }
  }
}

__device__ __forceinline__ void process_vec4(const f32x4& sv, const f32x4& lv,
                                             float& s_p, float& s_n, int& nn,
                                             float t[10]) {
  process_elem(sv[0], lv[0], s_p, s_n, nn, t);
  process_elem(sv[1], lv[1], s_p, s_n, nn, t);
  process_elem(sv[2], lv[2], s_p, s_n, nn, t);
  process_elem(sv[3], lv[3], s_p, s_n, nn, t);
}

// Inline-asm load: the compiler CANNOT sink this into the consume stream or
// shrink the in-flight window — the output regs are held until consumed.
#define GLOAD4(dst, ptr) \
  asm volatile("global_load_dwordx4 %0, %1, off" : "=v"(dst) : "v"(ptr))

// Counted wait, tied to the values consumed next: the "+v" operands create a
// register dependency so no use can be hoisted above the wait (rule #18),
// belt-and-braces with a sched_barrier at the call site.
#define VMWAIT_TIE(n, a, b) \
  asm volatile("s_waitcnt vmcnt(" #n ")" : "+v"(a), "+v"(b))

// One block per (row, part). Writes partial {sum_p, sum_n, count_n, top16}.
template <int SPLIT>
__global__ void __launch_bounds__(THREADS, 4) ranking_partial_kernel(
    const float* __restrict__ sim, const float* __restrict__ label,
    float* __restrict__ ws_sp, float* __restrict__ ws_sn,
    int* __restrict__ ws_cnt, float* __restrict__ ws_top) {
  const int blk = blockIdx.x;
  const int row = blk / SPLIT;
  const int part = blk % SPLIT;
  const int tid = threadIdx.x;
  const size_t base4 = (size_t)row * (N / 4) + (size_t)part * (N / (4 * SPLIT));
  const f32x4* sim4 = reinterpret_cast<const f32x4*>(sim) + base4;
  const f32x4* lab4 = reinterpret_cast<const f32x4*>(label) + base4;

  float s_p = 0.f, s_n = 0.f;
  int nn = 0;  // wave-uniform (ballot-popc accumulated)
  float t[10];
#pragma unroll
  for (int i = 0; i < 10; ++i) t[i] = PAD;

  constexpr int ITER = N / 4 / THREADS / SPLIT;  // 8 at SPLIT=8

  if constexpr (SPLIT == 8) {
    static_assert(ITER == 8, "asm pipeline assumes 8 load pairs");
    const f32x4* sp_ = sim4 + tid;
    const f32x4* lp_ = lab4 + tid;
    f32x4 sv0, sv1, sv2, sv3, sv4, sv5, sv6, sv7;
    f32x4 lv0, lv1, lv2, lv3, lv4, lv5, lv6, lv7;
    // Zero the vmem count so our hardcoded vmcnt values are exact. No
    // compiler vmem ops occur inside the region (pure-register compute).
    asm volatile("s_waitcnt vmcnt(0)" ::: "memory");
    // Issue burst: 16 dwordx4 (16 KB/lane-wave) in flight.
    GLOAD4(sv0, sp_ + 0 * THREADS);
    GLOAD4(lv0, lp_ + 0 * THREADS);
    GLOAD4(sv1, sp_ + 1 * THREADS);
    GLOAD4(lv1, lp_ + 1 * THREADS);
    GLOAD4(sv2, sp_ + 2 * THREADS);
    GLOAD4(lv2, lp_ + 2 * THREADS);
    GLOAD4(sv3, sp_ + 3 * THREADS);
    GLOAD4(lv3, lp_ + 3 * THREADS);
    GLOAD4(sv4, sp_ + 4 * THREADS);
    GLOAD4(lv4, lp_ + 4 * THREADS);
    GLOAD4(sv5, sp_ + 5 * THREADS);
    GLOAD4(lv5, lp_ + 5 * THREADS);
    GLOAD4(sv6, sp_ + 6 * THREADS);
    GLOAD4(lv6, lp_ + 6 * THREADS);
    GLOAD4(sv7, sp_ + 7 * THREADS);
    GLOAD4(lv7, lp_ + 7 * THREADS);
    // Consume in retirement order with counted waits (never drain early).
    VMWAIT_TIE(14, sv0, lv0);
    __builtin_amdgcn_sched_barrier(0);
    process_vec4(sv0, lv0, s_p, s_n, nn, t);
    VMWAIT_TIE(12, sv1, lv1);
    __builtin_amdgcn_sched_barrier(0);
    process_vec4(sv1, lv1, s_p, s_n, nn, t);
    VMWAIT_TIE(10, sv2, lv2);
    __builtin_amdgcn_sched_barrier(0);
    process_vec4(sv2, lv2, s_p, s_n, nn, t);
    VMWAIT_TIE(8, sv3, lv3);
    __builtin_amdgcn_sched_barrier(0);
    process_vec4(sv3, lv3, s_p, s_n, nn, t);
    VMWAIT_TIE(6, sv4, lv4);
    __builtin_amdgcn_sched_barrier(0);
    process_vec4(sv4, lv4, s_p, s_n, nn, t);
    VMWAIT_TIE(4, sv5, lv5);
    __builtin_amdgcn_sched_barrier(0);
    process_vec4(sv5, lv5, s_p, s_n, nn, t);
    VMWAIT_TIE(2, sv6, lv6);
    __builtin_amdgcn_sched_barrier(0);
    process_vec4(sv6, lv6, s_p, s_n, nn, t);
    VMWAIT_TIE(0, sv7, lv7);
    __builtin_amdgcn_sched_barrier(0);
    process_vec4(sv7, lv7, s_p, s_n, nn, t);
  } else {
    // Generic fallback (smaller SPLIT): plain batched loads.
#pragma unroll
    for (int it = 0; it < ITER; it += 4) {
      f32x4 sv[4], lv[4];
#pragma unroll
      for (int j = 0; j < 4; ++j) {
        sv[j] = sim4[(it + j) * THREADS + tid];
        lv[j] = lab4[(it + j) * THREADS + tid];
      }
#pragma unroll
      for (int j = 0; j < 4; ++j) process_vec4(sv[j], lv[j], s_p, s_n, nn, t);
    }
  }

  // expand to 16-list for bitonic merges (pad 0.2 keeps descending order)
  float tl[16];
#pragma unroll
  for (int i = 0; i < 10; ++i) tl[i] = t[i];
#pragma unroll
  for (int i = 10; i < 16; ++i) tl[i] = PAD;

  // intra-wave reductions
  s_p = wave_sum_f(s_p);
  s_n = wave_sum_f(s_n);
#pragma unroll
  for (int off = 1; off < 64; off <<= 1) merge_lists_shfl(tl, off);

  __shared__ float ls_p[4], ls_n[4];
  __shared__ int ls_c[4];
  __shared__ float ltop[4][16];
  const int wave = tid >> 6, lane = tid & 63;
  if (lane == 0) {
    ls_p[wave] = s_p;
    ls_n[wave] = s_n;
    ls_c[wave] = nn;
#pragma unroll
    for (int i = 0; i < 16; ++i) ltop[wave][i] = tl[i];
  }
  __syncthreads();

  if (wave == 0) {
    // lanes 0..3 each hold one wave's top-16; butterfly-merge them
    float m[16];
    if (lane < 4) {
#pragma unroll
      for (int i = 0; i < 16; ++i) m[i] = ltop[lane][i];
    } else {
#pragma unroll
      for (int i = 0; i < 16; ++i) m[i] = PAD;
    }
    merge_lists_shfl(m, 1);
    merge_lists_shfl(m, 2);

    float sp = (lane < 4) ? ls_p[lane] : 0.f;
    float sn = (lane < 4) ? ls_n[lane] : 0.f;
    int cn = (lane < 4) ? ls_c[lane] : 0;
    sp = wave_sum_f(sp);
    sn = wave_sum_f(sn);
#pragma unroll
    for (int off = 32; off >= 1; off >>= 1) cn += __shfl_xor(cn, off, 64);

    if (lane == 0) {
      ws_sp[blk] = sp;
      ws_sn[blk] = sn;
      ws_cnt[blk] = cn;
#pragma unroll
      for (int i = 0; i < 16; ++i) ws_top[blk * 16 + i] = m[i];
    }
  }
}

// One block, 256 threads: thread r combines the SPLIT partials of row r,
// computes the row loss, then the block reduces to the final mean.
template <int SPLIT>
__global__ void __launch_bounds__(256) combine_kernel(
    const float* __restrict__ ws_sp, const float* __restrict__ ws_sn,
    const int* __restrict__ ws_cnt, const float* __restrict__ ws_top,
    float* __restrict__ out) {
  const int r = threadIdx.x;
  const int p0 = r * SPLIT;

  float a[16];
#pragma unroll
  for (int i = 0; i < 16; ++i) a[i] = ws_top[p0 * 16 + i];
#pragma unroll
  for (int k = 1; k < SPLIT; ++k) {
    float b[16];
#pragma unroll
    for (int i = 0; i < 16; ++i) b[i] = ws_top[(p0 + k) * 16 + i];
    merge_lists_local(a, b);  // a = running top-16, sorted descending
  }

  float sp = 0.f, sn = 0.f;
  int cn = 0;
#pragma unroll
  for (int k = 0; k < SPLIT; ++k) {
    sp += ws_sp[p0 + k];
    sn += ws_sn[p0 + k];
    cn += ws_cnt[p0 + k];
  }

  // any positives <=> sp > 0 (each pos term >= exp(-40.96) > 0)
  float lse_p = (sp > 0.f) ? (C_OFF + __logf(sp)) : 0.f;
  float lse_n_all = (sn > 0.f) ? (C_OFF + __logf(sn)) : NEG_INF;

  // top-10 logsumexp (a[0..9] = top-10 negative sims; pad 0.2 -> logit 0, exact)
  float mx = NEG_INF;
  float lg[10];
#pragma unroll
  for (int i = 0; i < 10; ++i) {
    float v = a[i];
    float al = fmaxf(v - 0.2f, 0.f);
    float lo = al * (v - 0.2f) * 64.f;
    lg[i] = lo;
    mx = fmaxf(mx, lo);
  }
  float ss = 0.f;
#pragma unroll
  for (int i = 0; i < 10; ++i) ss += __expf(lg[i] - mx);
  float lse_n_top = mx + __logf(ss);

  float lse_n = (cn > 20) ? lse_n_top : lse_n_all;
  float x = lse_n + lse_p;
  // softplus(x) = max(x,0) + log1p(exp(-|x|))
  float loss = fmaxf(x, 0.f) + log1pf(__expf(-fabsf(x)));

  // block reduction (256 threads = 4 waves)
  float v = wave_sum_f(loss);
  __shared__ float wsh[4];
  if ((r & 63) == 0) wsh[r >> 6] = v;
  __syncthreads();
  if (r == 0) out[0] = (wsh[0] + wsh[1] + wsh[2] + wsh[3]) * (1.0f / 256.0f);
}

template <int SPLIT>
static void launch_all(const float* sim, const float* label, float* out,
                       float* wsf, hipStream_t stream) {
  constexpr int P = B * SPLIT;
  float* ws_sp = wsf;
  float* ws_sn = wsf + P;
  float* ws_top = wsf + 2 * P;
  int* ws_cnt = (int*)(wsf + 2 * P + P * 16);
  ranking_partial_kernel<SPLIT><<<dim3(P), dim3(THREADS), 0, stream>>>(
      sim, label, ws_sp, ws_sn, ws_cnt, ws_top);
  combine_kernel<SPLIT><<<dim3(1), dim3(256), 0, stream>>>(ws_sp, ws_sn, ws_cnt,
                                                           ws_top, out);
}

extern "C" void kernel_launch(void* const* d_in, const int* in_sizes, int n_in,
                              void* d_out, int out_size, void* d_ws, size_t ws_size,
                              hipStream_t stream) {
  const float* sim = (const float*)d_in[0];
  const float* label = (const float*)d_in[1];
  float* out = (float*)d_out;
  float* wsf = (float*)d_ws;

  auto need = [](int split) { return (size_t)B * split * 19 * sizeof(float); };
  if (ws_size >= need(8)) {
    launch_all<8>(sim, label, out, wsf, stream);
  } else if (ws_size >= need(4)) {
    launch_all<4>(sim, label, out, wsf, stream);
  } else {
    launch_all<2>(sim, label, out, wsf, stream);
  }
}

// Round 7
// 152.120 us; speedup vs baseline: 1.0236x; 1.0082x over previous
//
#include <hip/hip_runtime.h>
#include <cmath>

#define NEG_INF (-1.0e30f)

static constexpr int B = 256;
static constexpr int N = 65536;
static constexpr int THREADS = 256;          // 4 waves/block
static constexpr float C_OFF = 40.96f;       // = 64 * 0.8^2, upper bound of both logits
static constexpr float PAD = 0.2f;           // exact pad: logit(v<=0.2) == 0 == logit(0.2)

typedef float f32x4 __attribute__((ext_vector_type(4)));

__device__ __forceinline__ float wave_sum_f(float v) {
#pragma unroll
  for (int off = 32; off >= 1; off >>= 1) v += __shfl_xor(v, off, 64);
  return v;
}

// Merge this lane's descending-sorted 16-list with XOR-partner lane's list,
// keeping the top-16 of the union (bitonic top-k merge).
__device__ __forceinline__ void merge_lists_shfl(float t[16], int off) {
  float b[16];
#pragma unroll
  for (int i = 0; i < 16; ++i) b[i] = __shfl_xor(t[i], off, 64);
  float c[16];
#pragma unroll
  for (int i = 0; i < 16; ++i) c[i] = fmaxf(t[i], b[15 - i]);
#pragma unroll
  for (int s = 8; s >= 1; s >>= 1) {
#pragma unroll
    for (int i = 0; i < 16; ++i) {
      if ((i & s) == 0) {
        float lo = c[i], hi = c[i + s];
        c[i] = fmaxf(lo, hi);
        c[i + s] = fminf(lo, hi);
      }
    }
  }
#pragma unroll
  for (int i = 0; i < 16; ++i) t[i] = c[i];
}

// Same top-16 merge, but between two register lists (no shuffle).
__device__ __forceinline__ void merge_lists_local(float a[16], const float b[16]) {
  float c[16];
#pragma unroll
  for (int i = 0; i < 16; ++i) c[i] = fmaxf(a[i], b[15 - i]);
#pragma unroll
  for (int s = 8; s >= 1; s >>= 1) {
#pragma unroll
    for (int i = 0; i < 16; ++i) {
      if ((i & s) == 0) {
        float lo = c[i], hi = c[i + s];
        c[i] = fmaxf(lo, hi);
        c[i + s] = fminf(lo, hi);
      }
    }
  }
#pragma unroll
  for (int i = 0; i < 16; ++i) a[i] = c[i];
}

__device__ __forceinline__ void process_elem(float s, float l, float& s_p,
                                             float& s_n, int& nn, float t[10]) {
  const bool pos = l > 0.5f;
  const bool neg = l < 0.25f;
  // logit_p = 64*relu(0.8-s)^2 ; logit_n = 64*relu(s-0.2)^2 (both in [0, 40.96])
  float d = pos ? (0.8f - s) : (s - 0.2f);
  float r = fmaxf(d, 0.f);
  float arg = __builtin_fmaf(64.f * r, r, -C_OFF);  // <= 0, finite for all s
  float e = __expf(arg);
  if (pos) s_p += e;
  if (neg) s_n += e;
  // wave-uniform negative count on the SALU (no per-lane VALU add)
  nn += (int)__popcll(__ballot(neg));
  // sorted-descending top-10 insert. se=PAD for non-neg never triggers
  // (t[9] >= PAD invariant). Insert via v_med3: r[i] = med3(se, told[i-1], told[i])
  float se = neg ? s : PAD;
  if (se > t[9]) {
    float prev = t[0];
    t[0] = fmaxf(t[0], se);
#pragma unroll
    for (int i = 1; i < 10; ++i) {
      float cur = t[i];
      t[i] = __builtin_amdgcn_fmed3f(se, prev, cur);
      prev = cur;
    }
  }
}

__device__ __forceinline__ void process_vec4(const f32x4& sv, const f32x4& lv,
                                             float& s_p, float& s_n, int& nn,
                                             float t[10]) {
  process_elem(sv[0], lv[0], s_p, s_n, nn, t);
  process_elem(sv[1], lv[1], s_p, s_n, nn, t);
  process_elem(sv[2], lv[2], s_p, s_n, nn, t);
  process_elem(sv[3], lv[3], s_p, s_n, nn, t);
}

// Inline-asm load: the compiler CANNOT sink this into the consume stream or
// shrink the in-flight window — the output regs are held until consumed.
#define GLOAD4(dst, ptr) \
  asm volatile("global_load_dwordx4 %0, %1, off" : "=v"(dst) : "v"(ptr))

// Counted wait, tied to the values consumed next: the "+v" operands create a
// register dependency so no use can be hoisted above the wait (rule #18),
// belt-and-braces with a sched_barrier at the call site.
#define VMWAIT_TIE(n, a, b) \
  asm volatile("s_waitcnt vmcnt(" #n ")" : "+v"(a), "+v"(b))

// One block per (row, part). Writes partial {sum_p, sum_n, count_n, top10}.
template <int SPLIT>
__global__ void __launch_bounds__(THREADS, 4) ranking_partial_kernel(
    const float* __restrict__ sim, const float* __restrict__ label,
    float* __restrict__ ws_sp, float* __restrict__ ws_sn,
    int* __restrict__ ws_cnt, float* __restrict__ ws_top) {
  const int blk = blockIdx.x;
  const int row = blk / SPLIT;
  const int part = blk % SPLIT;
  const int tid = threadIdx.x;
  const size_t base4 = (size_t)row * (N / 4) + (size_t)part * (N / (4 * SPLIT));
  const f32x4* sim4 = reinterpret_cast<const f32x4*>(sim) + base4;
  const f32x4* lab4 = reinterpret_cast<const f32x4*>(label) + base4;

  float s_p = 0.f, s_n = 0.f;
  int nn = 0;  // wave-uniform (ballot-popc accumulated)
  float t[10];
#pragma unroll
  for (int i = 0; i < 10; ++i) t[i] = PAD;

  constexpr int ITER = N / 4 / THREADS / SPLIT;  // 8 (SPLIT=8) / 16 (SPLIT=4)
  static_assert(ITER % 8 == 0, "burst pipeline assumes multiples of 8 iters");

  // Chunked asm pipeline: per chunk, burst-issue 16 dwordx4 (16 KB/lane-wave
  // in flight), then consume in retirement order with counted vmcnt waits.
#pragma unroll 1
  for (int half = 0; half < ITER / 8; ++half) {
    const f32x4* sp_ = sim4 + half * 8 * THREADS + tid;
    const f32x4* lp_ = lab4 + half * 8 * THREADS + tid;
    f32x4 sv0, sv1, sv2, sv3, sv4, sv5, sv6, sv7;
    f32x4 lv0, lv1, lv2, lv3, lv4, lv5, lv6, lv7;
    // Zero the vmem count so hardcoded vmcnt values are exact (no compiler
    // vmem ops occur inside the region — pure-register compute).
    asm volatile("s_waitcnt vmcnt(0)" ::: "memory");
    GLOAD4(sv0, sp_ + 0 * THREADS);
    GLOAD4(lv0, lp_ + 0 * THREADS);
    GLOAD4(sv1, sp_ + 1 * THREADS);
    GLOAD4(lv1, lp_ + 1 * THREADS);
    GLOAD4(sv2, sp_ + 2 * THREADS);
    GLOAD4(lv2, lp_ + 2 * THREADS);
    GLOAD4(sv3, sp_ + 3 * THREADS);
    GLOAD4(lv3, lp_ + 3 * THREADS);
    GLOAD4(sv4, sp_ + 4 * THREADS);
    GLOAD4(lv4, lp_ + 4 * THREADS);
    GLOAD4(sv5, sp_ + 5 * THREADS);
    GLOAD4(lv5, lp_ + 5 * THREADS);
    GLOAD4(sv6, sp_ + 6 * THREADS);
    GLOAD4(lv6, lp_ + 6 * THREADS);
    GLOAD4(sv7, sp_ + 7 * THREADS);
    GLOAD4(lv7, lp_ + 7 * THREADS);
    VMWAIT_TIE(14, sv0, lv0);
    __builtin_amdgcn_sched_barrier(0);
    process_vec4(sv0, lv0, s_p, s_n, nn, t);
    VMWAIT_TIE(12, sv1, lv1);
    __builtin_amdgcn_sched_barrier(0);
    process_vec4(sv1, lv1, s_p, s_n, nn, t);
    VMWAIT_TIE(10, sv2, lv2);
    __builtin_amdgcn_sched_barrier(0);
    process_vec4(sv2, lv2, s_p, s_n, nn, t);
    VMWAIT_TIE(8, sv3, lv3);
    __builtin_amdgcn_sched_barrier(0);
    process_vec4(sv3, lv3, s_p, s_n, nn, t);
    VMWAIT_TIE(6, sv4, lv4);
    __builtin_amdgcn_sched_barrier(0);
    process_vec4(sv4, lv4, s_p, s_n, nn, t);
    VMWAIT_TIE(4, sv5, lv5);
    __builtin_amdgcn_sched_barrier(0);
    process_vec4(sv5, lv5, s_p, s_n, nn, t);
    VMWAIT_TIE(2, sv6, lv6);
    __builtin_amdgcn_sched_barrier(0);
    process_vec4(sv6, lv6, s_p, s_n, nn, t);
    VMWAIT_TIE(0, sv7, lv7);
    __builtin_amdgcn_sched_barrier(0);
    process_vec4(sv7, lv7, s_p, s_n, nn, t);
  }

  // expand to 16-list for bitonic merges (pad 0.2 keeps descending order)
  float tl[16];
#pragma unroll
  for (int i = 0; i < 10; ++i) tl[i] = t[i];
#pragma unroll
  for (int i = 10; i < 16; ++i) tl[i] = PAD;

  // intra-wave reductions
  s_p = wave_sum_f(s_p);
  s_n = wave_sum_f(s_n);
#pragma unroll
  for (int off = 1; off < 64; off <<= 1) merge_lists_shfl(tl, off);

  __shared__ float ls_p[4], ls_n[4];
  __shared__ int ls_c[4];
  __shared__ float ltop[4][16];
  const int wave = tid >> 6, lane = tid & 63;
  if (lane == 0) {
    ls_p[wave] = s_p;
    ls_n[wave] = s_n;
    ls_c[wave] = nn;
#pragma unroll
    for (int i = 0; i < 16; ++i) ltop[wave][i] = tl[i];
  }
  __syncthreads();

  if (wave == 0) {
    // lanes 0..3 each hold one wave's top-16; butterfly-merge them
    float m[16];
    if (lane < 4) {
#pragma unroll
      for (int i = 0; i < 16; ++i) m[i] = ltop[lane][i];
    } else {
#pragma unroll
      for (int i = 0; i < 16; ++i) m[i] = PAD;
    }
    merge_lists_shfl(m, 1);
    merge_lists_shfl(m, 2);

    float sp = (lane < 4) ? ls_p[lane] : 0.f;
    float sn = (lane < 4) ? ls_n[lane] : 0.f;
    int cn = (lane < 4) ? ls_c[lane] : 0;
    sp = wave_sum_f(sp);
    sn = wave_sum_f(sn);
#pragma unroll
    for (int off = 32; off >= 1; off >>= 1) cn += __shfl_xor(cn, off, 64);

    if (lane == 0) {
      ws_sp[blk] = sp;
      ws_sn[blk] = sn;
      ws_cnt[blk] = cn;
      // top-10 only (slots 10..15 are always PAD) -> 13 floats/partial,
      // so SPLIT=8 fits a 128 KB workspace (2048 * 52 B = 104 KB).
#pragma unroll
      for (int i = 0; i < 10; ++i) ws_top[blk * 10 + i] = m[i];
    }
  }
}

// One block, 256 threads: thread r combines the SPLIT partials of row r,
// computes the row loss, then the block reduces to the final mean.
template <int SPLIT>
__global__ void __launch_bounds__(256) combine_kernel(
    const float* __restrict__ ws_sp, const float* __restrict__ ws_sn,
    const int* __restrict__ ws_cnt, const float* __restrict__ ws_top,
    float* __restrict__ out) {
  const int r = threadIdx.x;
  const int p0 = r * SPLIT;

  float a[16];
#pragma unroll
  for (int i = 0; i < 10; ++i) a[i] = ws_top[p0 * 10 + i];
#pragma unroll
  for (int i = 10; i < 16; ++i) a[i] = PAD;
#pragma unroll
  for (int k = 1; k < SPLIT; ++k) {
    float b[16];
#pragma unroll
    for (int i = 0; i < 10; ++i) b[i] = ws_top[(p0 + k) * 10 + i];
#pragma unroll
    for (int i = 10; i < 16; ++i) b[i] = PAD;
    merge_lists_local(a, b);  // a = running top-16, sorted descending
  }

  float sp = 0.f, sn = 0.f;
  int cn = 0;
#pragma unroll
  for (int k = 0; k < SPLIT; ++k) {
    sp += ws_sp[p0 + k];
    sn += ws_sn[p0 + k];
    cn += ws_cnt[p0 + k];
  }

  // any positives <=> sp > 0 (each pos term >= exp(-40.96) > 0)
  float lse_p = (sp > 0.f) ? (C_OFF + __logf(sp)) : 0.f;
  float lse_n_all = (sn > 0.f) ? (C_OFF + __logf(sn)) : NEG_INF;

  // top-10 logsumexp (a[0..9] = top-10 negative sims; pad 0.2 -> logit 0, exact)
  float mx = NEG_INF;
  float lg[10];
#pragma unroll
  for (int i = 0; i < 10; ++i) {
    float v = a[i];
    float al = fmaxf(v - 0.2f, 0.f);
    float lo = al * (v - 0.2f) * 64.f;
    lg[i] = lo;
    mx = fmaxf(mx, lo);
  }
  float ss = 0.f;
#pragma unroll
  for (int i = 0; i < 10; ++i) ss += __expf(lg[i] - mx);
  float lse_n_top = mx + __logf(ss);

  float lse_n = (cn > 20) ? lse_n_top : lse_n_all;
  float x = lse_n + lse_p;
  // softplus(x) = max(x,0) + log1p(exp(-|x|))
  float loss = fmaxf(x, 0.f) + log1pf(__expf(-fabsf(x)));

  // block reduction (256 threads = 4 waves)
  float v = wave_sum_f(loss);
  __shared__ float wsh[4];
  if ((r & 63) == 0) wsh[r >> 6] = v;
  __syncthreads();
  if (r == 0) out[0] = (wsh[0] + wsh[1] + wsh[2] + wsh[3]) * (1.0f / 256.0f);
}

template <int SPLIT>
static void launch_all(const float* sim, const float* label, float* out,
                       float* wsf, hipStream_t stream) {
  constexpr int P = B * SPLIT;
  // layout (floats): sp[P] | sn[P] | top10[P*10] | cnt[P]  => 13 floats/partial
  float* ws_sp = wsf;
  float* ws_sn = wsf + P;
  float* ws_top = wsf + 2 * P;
  int* ws_cnt = (int*)(wsf + 2 * P + P * 10);
  ranking_partial_kernel<SPLIT><<<dim3(P), dim3(THREADS), 0, stream>>>(
      sim, label, ws_sp, ws_sn, ws_cnt, ws_top);
  combine_kernel<SPLIT><<<dim3(1), dim3(256), 0, stream>>>(ws_sp, ws_sn, ws_cnt,
                                                           ws_top, out);
}

extern "C" void kernel_launch(void* const* d_in, const int* in_sizes, int n_in,
                              void* d_out, int out_size, void* d_ws, size_t ws_size,
                              hipStream_t stream) {
  const float* sim = (const float*)d_in[0];
  const float* label = (const float*)d_in[1];
  float* out = (float*)d_out;
  float* wsf = (float*)d_ws;

  auto need = [](int split) { return (size_t)B * split * 13 * sizeof(float); };
  if (ws_size >= need(8)) {
    launch_all<8>(sim, label, out, wsf, stream);
  } else if (ws_size >= need(4)) {
    launch_all<4>(sim, label, out, wsf, stream);
  } else {
    launch_all<2>(sim, label, out, wsf, stream);
  }
}